// Round 1
// baseline (185.218 us; speedup 1.0000x reference)
//
#include <hip/hip_runtime.h>
#include <stdint.h>

// Problem constants (from reference)
#define B_SZ   512
#define T_SZ   100
#define NPRE   256
#define NPOST  256
#define KTOT   (B_SZ * T_SZ)      // 51200
#define SPLITS 64
#define KC_PER_BLOCK (KTOT / SPLITS)  // 800
#define CHUNKS (KC_PER_BLOCK / 32)    // 25

typedef __bf16 bf16x8 __attribute__((ext_vector_type(8)));
typedef float  floatx4 __attribute__((ext_vector_type(4)));
typedef uint32_t uintx4 __attribute__((ext_vector_type(4)));

// ---------------------------------------------------------------------------
// Kernel 1: exponential pre-trace, scan over t per (b,p), output bf16 in
// k-tiled layout trace_t[k>>5][p][k&31] so GEMM A-fragments are contiguous.
// trace[t] = decay*(trace[t-1] + pre[t-1]); trace[0] = 0.
// ---------------------------------------------------------------------------
__global__ __launch_bounds__(256) void stdp_trace_kernel(
    const float* __restrict__ pre, unsigned short* __restrict__ trace_t)
{
    const int b = blockIdx.x;       // batch
    const int p = threadIdx.x;      // pre-neuron
    const float decay = 0.95122942450071400910f;  // expf(-1/20) folds to fp32

    float carry = 0.0f;
    const float* src = pre + (size_t)b * T_SZ * NPRE + p;

    // t in steps of 4: k = b*100 + t is 4-aligned, stays inside one 32-tile
    for (int t0 = 0; t0 < T_SZ; t0 += 4) {
        unsigned short v[4];
#pragma unroll
        for (int j = 0; j < 4; ++j) {
            float x = src[(size_t)(t0 + j) * NPRE];
            // emit trace = carry (round-to-nearest-even bf16; carry >= 0, finite)
            uint32_t bits = __float_as_uint(carry);
            uint32_t rne  = (bits + 0x7FFFu + ((bits >> 16) & 1u)) >> 16;
            v[j] = (unsigned short)rne;
            carry = decay * (carry + x);
        }
        int k  = b * T_SZ + t0;
        int kc = k >> 5;
        int kk = k & 31;
        unsigned short* dst = trace_t + (((size_t)kc * 256 + p) << 5) + kk;
        *(ushort4*)dst = make_ushort4(v[0], v[1], v[2], v[3]);  // 8B, aligned
    }
}

// ---------------------------------------------------------------------------
// Kernel 2: split-K MFMA GEMM.  partial[bx] (128x128) += trace^T x post over
// this block's K-range.  256 blocks = 64 K-splits x (2 p-tiles x 2 q-tiles).
// No LDS, no barriers: A-frags are direct dwordx4 loads from k-tiled trace_t;
// B-frags are 8 coalesced strided dword loads from fp32 post, truncated to
// bf16 (exact: post in {0,1}) and packed with v_perm_b32.
// ---------------------------------------------------------------------------
__global__ __launch_bounds__(1024) void stdp_gemm_kernel(
    const unsigned short* __restrict__ trace_t,
    const float* __restrict__ post,
    float* __restrict__ partial)
{
    const int bx  = blockIdx.x;       // 0..255
    const int ks  = bx >> 2;          // K-split 0..63
    const int pt  = (bx >> 1) & 1;    // p-tile 0..1
    const int qt  = bx & 1;           // q-tile 0..1
    const int tid = threadIdx.x;
    const int wave = tid >> 6;        // 0..15
    const int lane = tid & 63;
    const int wp = wave & 3;          // wave p-region (32 rows)
    const int wq = wave >> 2;         // wave q-region (32 cols)
    const int l15 = lane & 15;
    const int l4  = lane >> 4;        // quad 0..3

    floatx4 acc[2][2] = {};

    const int p0 = pt * 128 + wp * 32;   // + f*16 + l15
    const int q0 = qt * 128 + wq * 32;
    const int kc0 = ks * CHUNKS;

    // A: element index ((kc*256 + p)*32 + l4*8); lane holds A[m=l15][k=l4*8+j]
    const unsigned short* Abase =
        trace_t + (((size_t)kc0 * 256 + p0 + l15) << 5) + l4 * 8;
    // B: post[(kc*32 + l4*8 + j)*256 + q]; lane holds B[k=l4*8+j][n=l15]
    const float* Bbase = post + ((size_t)kc0 * 32 + l4 * 8) * 256 + q0 + l15;

#pragma unroll 2
    for (int c = 0; c < CHUNKS; ++c) {
        bf16x8 afrag[2], bfrag[2];
#pragma unroll
        for (int f = 0; f < 2; ++f) {
            afrag[f] = *(const bf16x8*)(Abase + ((f * 16) << 5));
        }
#pragma unroll
        for (int f = 0; f < 2; ++f) {
            float x[8];
#pragma unroll
            for (int j = 0; j < 8; ++j)
                x[j] = Bbase[(size_t)j * 256 + f * 16];
            uintx4 pk;
#pragma unroll
            for (int j = 0; j < 4; ++j)
                pk[j] = __builtin_amdgcn_perm(__float_as_uint(x[2 * j + 1]),
                                              __float_as_uint(x[2 * j]),
                                              0x07060302u);  // [x1.hi16, x0.hi16]
            bfrag[f] = __builtin_bit_cast(bf16x8, pk);
        }
#pragma unroll
        for (int fp = 0; fp < 2; ++fp)
#pragma unroll
            for (int fq = 0; fq < 2; ++fq)
                acc[fp][fq] = __builtin_amdgcn_mfma_f32_16x16x32_bf16(
                    afrag[fp], bfrag[fq], acc[fp][fq], 0, 0, 0);

        Abase += 256 * 32;   // next kc tile
        Bbase += 32 * 256;   // next 32 k rows
    }

    // C/D layout (m89/m91-verified): col = lane&15, row = (lane>>4)*4 + reg
    float* pout = partial + (size_t)bx * (128 * 128);
#pragma unroll
    for (int fp = 0; fp < 2; ++fp) {
#pragma unroll
        for (int fq = 0; fq < 2; ++fq) {
            int r0 = wp * 32 + fp * 16 + l4 * 4;
            int cq = wq * 32 + fq * 16 + l15;
#pragma unroll
            for (int v = 0; v < 4; ++v)
                pout[(size_t)(r0 + v) * 128 + cq] = acc[fp][fq][v];
        }
    }
}

// ---------------------------------------------------------------------------
// Kernel 3: reduce 64 K-split partials, apply (A+ - A-)/(B*T).
// ---------------------------------------------------------------------------
__global__ __launch_bounds__(256) void stdp_reduce_kernel(
    const float* __restrict__ partial, float* __restrict__ out)
{
    const int idx = blockIdx.x * 256 + threadIdx.x;  // 0..65535
    const int P = idx >> 8, Q = idx & 255;
    const int pt = P >> 7, i = P & 127;
    const int qt = Q >> 7, j = Q & 127;

    const float* src = partial + ((size_t)(pt * 2 + qt) * 128 + i) * 128 + j;
    float s = 0.0f;
#pragma unroll 4
    for (int ks = 0; ks < SPLITS; ++ks)
        s += src[(size_t)ks * 4 * 128 * 128];

    const float scale = (0.005f - 0.00525f) * (1.0f / (float)KTOT);
    out[idx] = s * scale;
}

// ---------------------------------------------------------------------------
extern "C" void kernel_launch(void* const* d_in, const int* in_sizes, int n_in,
                              void* d_out, int out_size, void* d_ws, size_t ws_size,
                              hipStream_t stream)
{
    const float* pre  = (const float*)d_in[0];   // [512,100,256]
    const float* post = (const float*)d_in[1];   // [512,100,256]
    // d_in[2] = weights: only defines output shape; values unused.
    float* out = (float*)d_out;                  // [256,256]

    // Workspace layout: trace_t (bf16, k-tiled) then partials.
    unsigned short* trace_t = (unsigned short*)d_ws;                  // 51200*256*2 = 26,214,400 B
    float* partial = (float*)((char*)d_ws + (size_t)KTOT * 256 * 2);  // 256*128*128*4 = 16,777,216 B

    stdp_trace_kernel<<<B_SZ, 256, 0, stream>>>(pre, trace_t);
    stdp_gemm_kernel<<<256, 1024, 0, stream>>>(trace_t, post, partial);
    stdp_reduce_kernel<<<256, 256, 0, stream>>>(partial, out);
}

// Round 2
// 180.515 us; speedup vs baseline: 1.0261x; 1.0261x over previous
//
#include <hip/hip_runtime.h>
#include <stdint.h>

// Problem constants (from reference)
#define B_SZ   512
#define T_SZ   100
#define NPRE   256
#define NPOST  256
#define KTOT   (B_SZ * T_SZ)          // 51200
#define SPLITS 64
#define KC_PER_BLOCK (KTOT / SPLITS)  // 800
#define CHUNKS (KC_PER_BLOCK / 32)    // 25

typedef __bf16 bf16x8 __attribute__((ext_vector_type(8)));
typedef float  floatx4 __attribute__((ext_vector_type(4)));

// ---------------------------------------------------------------------------
// Kernel 1 (fused prep): blocks 0..511 compute the exponential pre-trace
// (fp32 scan, RNE->bf16); blocks 512..1023 truncate-pack post (exact: {0,1}).
// Both write bf16 in k-tiled layout X_t[k>>5][n][k&31] so GEMM fragments are
// single dwordx4 loads. Loads are issued 20-deep before the carry chain.
// ---------------------------------------------------------------------------
__global__ __launch_bounds__(256) void stdp_prep_kernel(
    const float* __restrict__ pre, const float* __restrict__ post,
    unsigned short* __restrict__ trace_t, unsigned short* __restrict__ post_t)
{
    const int bid = blockIdx.x;
    const int p = threadIdx.x;

    if (bid < B_SZ) {
        const int b = bid;
        const float decay = 0.95122942450071400910f;  // expf(-1/20)
        const float* src = pre + (size_t)b * T_SZ * NPRE + p;
        float carry = 0.0f;
        for (int t0 = 0; t0 < T_SZ; t0 += 20) {
            float x[20];
#pragma unroll
            for (int j = 0; j < 20; ++j)
                x[j] = src[(size_t)(t0 + j) * NPRE];
#pragma unroll
            for (int g = 0; g < 5; ++g) {
                unsigned short v[4];
#pragma unroll
                for (int j = 0; j < 4; ++j) {
                    // emit trace = carry (RNE to bf16; carry >= 0, finite)
                    uint32_t bits = __float_as_uint(carry);
                    v[j] = (unsigned short)((bits + 0x7FFFu + ((bits >> 16) & 1u)) >> 16);
                    carry = decay * (carry + x[g * 4 + j]);
                }
                int k = b * T_SZ + t0 + g * 4;  // 4-aligned, never crosses 32-tile
                unsigned short* dst =
                    trace_t + (((size_t)(k >> 5) * 256 + p) << 5) + (k & 31);
                *(ushort4*)dst = make_ushort4(v[0], v[1], v[2], v[3]);
            }
        }
    } else {
        const int b = bid - B_SZ;
        const float* src = post + (size_t)b * T_SZ * NPOST + p;
        for (int t0 = 0; t0 < T_SZ; t0 += 20) {
            float x[20];
#pragma unroll
            for (int j = 0; j < 20; ++j)
                x[j] = src[(size_t)(t0 + j) * NPOST];
#pragma unroll
            for (int g = 0; g < 5; ++g) {
                unsigned short v[4];
#pragma unroll
                for (int j = 0; j < 4; ++j)
                    v[j] = (unsigned short)(__float_as_uint(x[g * 4 + j]) >> 16);
                int k = b * T_SZ + t0 + g * 4;
                unsigned short* dst =
                    post_t + (((size_t)(k >> 5) * 256 + p) << 5) + (k & 31);
                *(ushort4*)dst = make_ushort4(v[0], v[1], v[2], v[3]);
            }
        }
    }
}

// ---------------------------------------------------------------------------
// Kernel 2: split-K MFMA GEMM. 256 blocks = 64 K-splits x (2 p-tiles x 2
// q-tiles of 128). No LDS/barriers: A and B frags are direct dwordx4 loads
// from the k-tiled bf16 arrays, with explicit next-chunk register prefetch.
// ---------------------------------------------------------------------------
__global__ __launch_bounds__(1024) void stdp_gemm_kernel(
    const unsigned short* __restrict__ trace_t,
    const unsigned short* __restrict__ post_t,
    float* __restrict__ partial)
{
    const int bx  = blockIdx.x;       // 0..255
    const int ks  = bx >> 2;          // K-split 0..63
    const int pt  = (bx >> 1) & 1;
    const int qt  = bx & 1;
    const int tid = threadIdx.x;
    const int wave = tid >> 6;        // 0..15
    const int lane = tid & 63;
    const int wp = wave & 3;          // wave p-region (32 rows)
    const int wq = wave >> 2;         // wave q-region (32 cols)
    const int l15 = lane & 15;
    const int l4  = lane >> 4;        // quad 0..3

    const int p0 = pt * 128 + wp * 32;
    const int q0 = qt * 128 + wq * 32;
    const int kc0 = ks * CHUNKS;

    // lane holds A[m=l15][k=l4*8+j] and B[k=l4*8+j][n=l15]
    const unsigned short* Abase =
        trace_t + (((size_t)kc0 * 256 + p0 + l15) << 5) + l4 * 8;
    const unsigned short* Bbase =
        post_t + (((size_t)kc0 * 256 + q0 + l15) << 5) + l4 * 8;

    floatx4 acc[2][2] = {};

    bf16x8 a0 = *(const bf16x8*)(Abase);
    bf16x8 a1 = *(const bf16x8*)(Abase + 512);   // +16 rows
    bf16x8 b0 = *(const bf16x8*)(Bbase);
    bf16x8 b1 = *(const bf16x8*)(Bbase + 512);

#pragma unroll
    for (int c = 0; c < CHUNKS; ++c) {
        bf16x8 na0, na1, nb0, nb1;
        if (c + 1 < CHUNKS) {
            size_t off = (size_t)(c + 1) * (256 * 32);
            na0 = *(const bf16x8*)(Abase + off);
            na1 = *(const bf16x8*)(Abase + off + 512);
            nb0 = *(const bf16x8*)(Bbase + off);
            nb1 = *(const bf16x8*)(Bbase + off + 512);
        }
        acc[0][0] = __builtin_amdgcn_mfma_f32_16x16x32_bf16(a0, b0, acc[0][0], 0, 0, 0);
        acc[0][1] = __builtin_amdgcn_mfma_f32_16x16x32_bf16(a0, b1, acc[0][1], 0, 0, 0);
        acc[1][0] = __builtin_amdgcn_mfma_f32_16x16x32_bf16(a1, b0, acc[1][0], 0, 0, 0);
        acc[1][1] = __builtin_amdgcn_mfma_f32_16x16x32_bf16(a1, b1, acc[1][1], 0, 0, 0);
        if (c + 1 < CHUNKS) {
            a0 = na0; a1 = na1; b0 = nb0; b1 = nb1;
        }
    }

    // C/D layout (m89/m91-verified): col = lane&15, row = (lane>>4)*4 + reg
    float* pout = partial + (size_t)bx * (128 * 128);
#pragma unroll
    for (int fp = 0; fp < 2; ++fp) {
#pragma unroll
        for (int fq = 0; fq < 2; ++fq) {
            int r0 = wp * 32 + fp * 16 + l4 * 4;
            int cq = wq * 32 + fq * 16 + l15;
#pragma unroll
            for (int v = 0; v < 4; ++v)
                pout[(size_t)(r0 + v) * 128 + cq] = acc[fp][fq][v];
        }
    }
}

// ---------------------------------------------------------------------------
// Kernel 3a: reduce 64 K-splits -> 8 (8-deep chains, 8192 waves).
// partial[(ks*4+tile)*16384 + i] == partial[ks*65536 + e],  e = tile*16384+i
// ---------------------------------------------------------------------------
__global__ __launch_bounds__(256) void stdp_reduce1_kernel(
    const float* __restrict__ partial, float* __restrict__ tmp)
{
    const int tid = blockIdx.x * 256 + threadIdx.x;  // 0..524287
    const int group = tid >> 16;                     // 0..7
    const int e = tid & 65535;
    const float* src = partial + (size_t)group * 8 * 65536 + e;
    float s = 0.0f;
#pragma unroll
    for (int k2 = 0; k2 < 8; ++k2)
        s += src[(size_t)k2 * 65536];
    tmp[tid] = s;
}

// ---------------------------------------------------------------------------
// Kernel 3b: reduce 8 -> 1, un-tile, apply (A+ - A-)/(B*T).
// ---------------------------------------------------------------------------
__global__ __launch_bounds__(256) void stdp_reduce2_kernel(
    const float* __restrict__ tmp, float* __restrict__ out)
{
    const int idx = blockIdx.x * 256 + threadIdx.x;  // 0..65535
    const int P = idx >> 8, Q = idx & 255;
    const int e = ((P >> 7) * 2 + (Q >> 7)) * 16384 + (P & 127) * 128 + (Q & 127);
    float s = 0.0f;
#pragma unroll
    for (int g = 0; g < 8; ++g)
        s += tmp[(size_t)g * 65536 + e];
    const float scale = (0.005f - 0.00525f) * (1.0f / (float)KTOT);
    out[idx] = s * scale;
}

// ---------------------------------------------------------------------------
extern "C" void kernel_launch(void* const* d_in, const int* in_sizes, int n_in,
                              void* d_out, int out_size, void* d_ws, size_t ws_size,
                              hipStream_t stream)
{
    const float* pre  = (const float*)d_in[0];   // [512,100,256]
    const float* post = (const float*)d_in[1];   // [512,100,256]
    float* out = (float*)d_out;                  // [256,256]

    // Workspace: trace_t | post_t | partial.  tmp aliases trace_t (dead after GEMM).
    unsigned short* trace_t = (unsigned short*)d_ws;                       // 26,214,400 B
    unsigned short* post_t  = trace_t + (size_t)KTOT * 256;                // 26,214,400 B
    float* partial = (float*)((char*)d_ws + 2 * (size_t)KTOT * 256 * 2);   // 16,777,216 B
    float* tmp = (float*)d_ws;                                             // 2 MB alias

    stdp_prep_kernel<<<1024, 256, 0, stream>>>(pre, post, trace_t, post_t);
    stdp_gemm_kernel<<<256, 1024, 0, stream>>>(trace_t, post_t, partial);
    stdp_reduce1_kernel<<<2048, 256, 0, stream>>>(partial, tmp);
    stdp_reduce2_kernel<<<256, 256, 0, stream>>>(tmp, out);
}